// Round 13
// baseline (110.076 us; speedup 1.0000x reference)
//
#include <hip/hip_runtime.h>
#include <math.h>

#define CIN   16
#define COUT  64
#define H     256
#define W     256
#define OH    254
#define OW    254
#define NTAP  9
#define HWSZ  (H * W)
#define TOR   8            // out rows per tile
#define TIR   10           // input rows staged per tile
#define SROW  264          // f16x8 slots per row region: 2 g * 132 px (linear, conflict-free)
#define BUFS  (TIR * SROW) // 2640 slots = 42,240 B per buffer
#define NTILE 16

typedef _Float16 f16x8  __attribute__((ext_vector_type(8)));
typedef float    f32x16 __attribute__((ext_vector_type(16)));

// weight pack: [tap 9][msub 2][lane 64][e 8] fp16; co=(l&31)+32m, cin=8*(l>>5)+e
__global__ void wpack_kernel(const float* __restrict__ w, _Float16* __restrict__ wpk) {
    int idx = blockIdx.x * 256 + threadIdx.x;   // 0..9215
    if (idx >= NTAP * 2 * 64 * 8) return;
    int e = idx & 7, l = (idx >> 3) & 63, m = (idx >> 9) & 1, t = idx >> 10;
    int co  = (l & 31) + 32 * m;
    int cin = 8 * (l >> 5) + e;
    wpk[idx] = (_Float16)w[((co * CIN + cin) * 3 + t / 3) * 3 + (t % 3)];
}

__device__ __forceinline__ float tanh_fast(float v) {
    float e = __expf(2.0f * v);
    return 1.0f - 2.0f * __builtin_amdgcn_rcpf(e + 1.0f);
}
__device__ __forceinline__ float min3f(float a, float b, float c) {
    return fminf(fminf(a, b), c);   // clang fuses to v_min3_f32
}

// 512 thr = 8 waves; block = (img, col, half): marches 16 tiles of 8 rows x 128 px.
// Double-buffered LDS; tile t+1's loads issued BEFORE tile t's compute, written
// after it -> HBM streams under MFMA continuously. Grid 256 = exactly 1 block/CU.
__global__ __launch_bounds__(512, 2) void conv_mfma_kernel(
        const float* __restrict__ x, const f16x8* __restrict__ wpk,
        const float* __restrict__ bias, float* __restrict__ out) {
    __shared__ f16x8 xs[2][BUFS];   // 84,480 B

    const int tid  = threadIdx.x;
    const int lane = tid & 63;

    int bid = blockIdx.x;
    int nb  = (bid & 7) * 32 + (bid >> 3);   // 256 = 8*32 bijective XCD swizzle
    const int img  = nb >> 2;
    const int half = (nb >> 1) & 1;          // 128-row half
    const int col  = nb & 1;                 // 128-px column
    const int base = col * 124;              // staged global px origin (132 wide)
    const int P0   = col * 128;              // output px origin
    const int R0   = half * 128;

    const float* xb = x + (size_t)img * CIN * HWSZ;

    // ---- weights: global -> 72 VGPRs (loop-invariant) ----
    f16x8 wreg[NTAP][2];
#pragma unroll
    for (int t = 0; t < NTAP; ++t)
#pragma unroll
        for (int m = 0; m < 2; ++m)
            wreg[t][m] = wpk[(t * 2 + m) * 64 + lane];

    // ---- staging unit decode: u = tid + 512k -> (row, g, px-pair); 1320 units ----
    int row_[3], g_[3], pp_[3];
#pragma unroll
    for (int k = 0; k < 3; ++k) {
        int u = tid + 512 * k;
        row_[k] = u / 132;
        int rem = u - 132 * row_[k];
        g_[k]  = (rem >= 66) ? 1 : 0;
        pp_[k] = rem - 66 * g_[k];
    }
    const bool act2 = (tid < 296);           // 1320 - 1024

#define SLOADK(k, rbase, vv)                                                    \
    {                                                                           \
        int grow = (rbase) + row_[k]; if (grow > 255) grow = 255;               \
        const float* gp = xb + (size_t)g_[k] * 8 * HWSZ + (size_t)grow * W      \
                             + base + 2 * pp_[k];                               \
        _Pragma("unroll")                                                       \
        for (int c = 0; c < 8; ++c) vv[c] = *(const float2*)(gp + (size_t)c * HWSZ); \
    }

#define SWRITEK(k, bufp, vv)                                                    \
    {                                                                           \
        f16x8 q0, q1;                                                           \
        _Pragma("unroll")                                                       \
        for (int c = 0; c < 8; ++c) { q0[c] = (_Float16)vv[c].x;                \
                                      q1[c] = (_Float16)vv[c].y; }              \
        int sl_ = row_[k] * SROW + g_[k] * 132 + 2 * pp_[k];                    \
        (bufp)[sl_]     = q0;                                                   \
        (bufp)[sl_ + 1] = q1;                                                   \
    }

    // ---- prologue: stage tile 0 into buffer 0 ----
    {
        float2 v0[8], v1[8], v2[8];
        SLOADK(0, R0, v0)
        SLOADK(1, R0, v1)
        if (act2) SLOADK(2, R0, v2)
        SWRITEK(0, xs[0], v0)
        SWRITEK(1, xs[0], v1)
        if (act2) SWRITEK(2, xs[0], v2)
    }

    const int wave = tid >> 6;
    const int pr   = wave >> 2;              // pair parity (0/1)
    const int sl4  = wave & 3;               // 32-px slice
    const int l31  = lane & 31;
    const int g2   = lane >> 5;

    // fragment read offsets (loop-invariant, linear layout)
    int roff[3];
#pragma unroll
    for (int kw = 0; kw < 3; ++kw) {
        int lp = (col ? 4 : 0) + 32 * sl4 + l31 + kw;
        if (lp > 131) lp = 131;              // only feeds masked outputs
        roff[kw] = g2 * 132 + lp;
    }

    // bias as MFMA C-fragment: col=l31(px), row=(r&3)+8*(r>>2)+4*g2+32m (co)
    f32x16 cbias[2];
#pragma unroll
    for (int m = 0; m < 2; ++m)
#pragma unroll
        for (int r = 0; r < 16; ++r)
            cbias[m][r] = bias[(r & 3) + 8 * (r >> 2) + 4 * g2 + 32 * m];

    __syncthreads();

    float2 vA[8], vB[8], vC[8];
    int cur = 0;

#pragma unroll 1
    for (int t = 0; t < NTILE; ++t) {
        const int r0 = R0 + t * TOR;
        const bool pf = (t + 1 < NTILE);

        // issue-early: full load burst for tile t+1 (completes under compute)
        if (pf) {
            const int rn = r0 + TOR;
            SLOADK(0, rn, vA)
            SLOADK(1, rn, vB)
            if (act2) SLOADK(2, rn, vC)
        }
        __builtin_amdgcn_sched_barrier(0);

        const f16x8* bufc = &xs[cur][0];

        // ---- compute tile t: 2 iters, pure LDS ----
#pragma unroll
        for (int i = 0; i < 2; ++i) {
            f32x16 acc[2][2];   // [ro][m]
#pragma unroll
            for (int dd = 0; dd < 4; ++dd) {
                const f16x8* xr = bufc + (4 * i + 2 * pr + dd) * SROW;
                f16x8 f0 = xr[roff[0]];
                f16x8 f1 = xr[roff[1]];
                f16x8 f2 = xr[roff[2]];
#pragma unroll
                for (int ro = 0; ro < 2; ++ro) {
                    const int kh = dd - ro;
                    if (kh < 0 || kh > 2) continue;
#pragma unroll
                    for (int m = 0; m < 2; ++m) {
                        if (kh == 0)
                            acc[ro][m] = __builtin_amdgcn_mfma_f32_32x32x16_f16(wreg[0][m], f0, cbias[m], 0, 0, 0);
                        else
                            acc[ro][m] = __builtin_amdgcn_mfma_f32_32x32x16_f16(wreg[kh * 3][m], f0, acc[ro][m], 0, 0, 0);
                        acc[ro][m] = __builtin_amdgcn_mfma_f32_32x32x16_f16(wreg[kh * 3 + 1][m], f1, acc[ro][m], 0, 0, 0);
                        acc[ro][m] = __builtin_amdgcn_mfma_f32_32x32x16_f16(wreg[kh * 3 + 2][m], f2, acc[ro][m], 0, 0, 0);
                    }
                }
            }
            // epilogue: min over 64 cout -> tanh(tanh) -> store
#pragma unroll
            for (int ro = 0; ro < 2; ++ro) {
                const int oh = r0 + 4 * i + 2 * pr + ro;
                float mn = fminf(acc[ro][0][0], acc[ro][1][0]);
#pragma unroll
                for (int q = 1; q < 16; ++q)
                    mn = min3f(acc[ro][0][q], acc[ro][1][q], mn);
                mn = fminf(mn, __shfl_xor(mn, 32));
                float t2 = tanh_fast(tanh_fast(mn));
                const int px = P0 + 32 * sl4 + l31;
                if (g2 == 0 && px < OW && oh < OH)
                    out[((size_t)img * OH + oh) * OW + px] = t2;
            }
        }
        __builtin_amdgcn_sched_barrier(0);

        // write-late: tile t+1 -> other buffer (vmcnt wait lands here, not in compute)
        if (pf) {
            f16x8* bufn = &xs[cur ^ 1][0];
            SWRITEK(0, bufn, vA)
            SWRITEK(1, bufn, vB)
            if (act2) SWRITEK(2, bufn, vC)
        }
        __syncthreads();
        cur ^= 1;
    }
}

extern "C" void kernel_launch(void* const* d_in, const int* in_sizes, int n_in,
                              void* d_out, int out_size, void* d_ws, size_t ws_size,
                              hipStream_t stream) {
    const float* x    = (const float*)d_in[0];
    const float* w    = (const float*)d_in[1];
    const float* bias = (const float*)d_in[2];
    float* out = (float*)d_out;
    _Float16* wpk = (_Float16*)d_ws;   // 9216 fp16 = 18,432 B

    wpack_kernel<<<36, 256, 0, stream>>>(w, wpk);
    conv_mfma_kernel<<<256, 512, 0, stream>>>(x, (const f16x8*)wpk, bias, out);
}